// Round 10
// baseline (585.309 us; speedup 1.0000x reference)
//
#include <hip/hip_runtime.h>

// gConv3d separable factorization:
//   q[n,o,b,h,w]   = sum_{c,f} x[c, n+f, h, w] * weight[o,c,f,b]        (K=216)
//   s[n,g,o,ii,jj] = sum_{b,u,v} q[n,o,b,ii+u,jj+v] * basis[g][(b,u,v)] (K=63)
//   out[g*8+o, xo+1,yo+1,zo+1, h, w] = s[n, T(g,h,w), o, clip(h)-1, clip(w)-1] + bias_sum[o]
// T(g,h,w) = (g+1)%12 on the (h,w) border, else g. Non-interior xyz = 0.
//
// R14 = R13 resubmitted verbatim (R13 bench died with "container failed
// twice" — same infra signature as R8, which passed on verbatim resubmit.
// Kernel re-audited: vmcnt waits can't deadlock, LDS/global indices in
// bounds, barriers block-uniform, global_load_lds dest wave-uniform.)
//
// R13 rationale. Verdict from R10/R11/R12: hipcc will NOT hold a load batch
// in VGPRs — scheduler sinks it (R10, VGPR 28, serial MLP=1) or allocator
// spills it (R11 +296MB, R12 +52MB scratch; R12's VALUBusy 62% proved the
// pipeline idea works but register cost killed it). Escape hatch with ZERO
// register cost: __builtin_amdgcn_global_load_lds (fire-and-forget
// VMEM->LDS, vmcnt-tracked, no dest VGPR; compiler never auto-emits it).
// Structure: WAVE-PRIVATE staging slices -> no __syncthreads in stage-1:
//   - wave w stages its own 64-float slice of each of the 27 tap rows of
//     channel c+1 (src = row + w*64 + lane; LDS dest = uniform + lane*4),
//     then s_waitcnt vmcnt(27) (counted, never 0 mid-loop) ensures c's 27
//     landed (they flew during c-1's 1512-cyc FMA phase), then 27
//     ds_read_b32 (conflict-free) + 756 FMAs.
//   - LDS: 5 waves x 2 bufs x 27 rows x 256 B = 69120 B; qs (17920 B)
//     ALIASES the staging buffer (dead after stage-1), barrier-protected.
//     -> 2 blocks/CU (10 waves). Per-wave duty 6% -> ~80%, so 2.5
//     waves/SIMD saturate.
// Sentinels: WRITE_SIZE == 207360 KB exactly AND VGPR 45-60 (nothing can
// spill); if VALUBusy still ~45% with clean sentinels -> stall is not VMEM,
// get a disasm dump before further edits.
// Predict: VALUBusy 43 -> 75-90%, dur 181 -> 100-125 us.

#define HW 320
#define OG 2          // o's per block (4 blocks per n)
#define NLOG 2916     // 729 n * 4 o-quarters
#define NPAD 2928     // 8 * 366

typedef __attribute__((address_space(3))) float       lds_f;
typedef __attribute__((address_space(1)))  const float glb_f;

__global__ __launch_bounds__(320, 4) void fused_kernel(
    const float* __restrict__ x, const float* __restrict__ weight,
    const float* __restrict__ bias, const float* __restrict__ basis,
    float* __restrict__ out)
{
    // staging: [wave][buf][tap][lane] = 5*2*27*64 floats = 69120 B.
    // qs (OG*7*HW = 4480 floats) aliases the front; stage-1 data is dead
    // by then and both transitions are __syncthreads-protected.
    __shared__ float smem[5 * 2 * 27 * 64];

    const int tid  = threadIdx.x;
    const int lane = tid & 63;
    const int wbase = (tid >> 6) * (2 * 27 * 64);   // wave's private slice

    // ---- border zero-fill (grid-strided, masked, coalesced) ----
    {
        float4* out4 = (float4*)out;
        const float4 z = make_float4(0.f, 0.f, 0.f, 0.f);
        for (int s = blockIdx.x * 320 + tid; s < 96 * 1728 * 80; s += NPAD * 320) {
            int row = s / 80;                      // go*1728 + xyz
            int xyz = row - (row / 1728) * 1728;
            int xi = xyz / 144;
            int r2 = xyz - xi * 144;
            int yi = r2 / 12;
            int zi = r2 - yi * 12;
            if (!((unsigned)(xi - 1) < 9u && (unsigned)(yi - 1) < 9u &&
                  (unsigned)(zi - 1) < 9u))
                out4[s] = z;
        }
    }
    // drain zero-fill stores so counted vmcnt waits below are exact
    asm volatile("s_waitcnt vmcnt(0)" ::: "memory");

    // XCD-aware swizzle: contiguous logical range per XCD; all 4 o-blocks of
    // one n stay on the same XCD (they share all 216 x taps).
    const int xcd  = blockIdx.x & 7;
    const int slot = blockIdx.x >> 3;
    const int logical = xcd * (NPAD / 8) + slot;
    if (logical >= NLOG) return;

    const int n  = logical >> 2;
    const int o0 = (logical & 3) * OG;
    const int xo = n / 81;
    const int rem = n - xo * 81;
    const int yo = rem / 9;
    const int zo = rem - yo * 9;

    // ---------------- stage 1: async LDS staging + FMA ----------------
    float acc[OG * 7];
    #pragma unroll
    for (int i = 0; i < OG * 7; ++i) acc[i] = 0.f;

    // per-lane global base: +tid == + (wave*64 + lane)
    const float* xb = x + ((xo * 12 + yo) * 12 + zo) * HW + tid;

    // issue the 27 tap-slices of channel cc into buffer p (no dest VGPRs)
    #define ISSUE_C(cc, p) {                                                  \
        const float* xsrc = xb + (cc) * 1728 * HW;                            \
        _Pragma("unroll")                                                     \
        for (int t = 0; t < 27; ++t) {                                        \
            const int fi = t / 9, fj = (t / 3) % 3, fk = t % 3;               \
            __builtin_amdgcn_global_load_lds(                                 \
                (glb_f*)(xsrc + (fi * 144 + fj * 12 + fk) * HW),              \
                (lds_f*)&smem[wbase + (p) * (27 * 64) + t * 64],              \
                4, 0, 0);                                                     \
        }                                                                     \
    }

    #define COMPUTE_C(cc, p) {                                                \
        const float* wc = weight + o0 * 1512 + (cc) * 189; /* -> s_load */    \
        _Pragma("unroll")                                                     \
        for (int t = 0; t < 27; ++t) {                                        \
            const int fi = t / 9, fj = (t / 3) % 3, fk = t % 3;               \
            float xval = smem[wbase + (p) * (27 * 64) + t * 64 + lane];       \
            const float* wp = wc + fi * 63 + fj * 21 + fk * 7;                \
            _Pragma("unroll")                                                 \
            for (int oo = 0; oo < OG; ++oo)                                   \
                _Pragma("unroll")                                             \
                for (int b = 0; b < 7; ++b)                                   \
                    acc[oo * 7 + b] = fmaf(xval, wp[oo * 1512 + b],           \
                                           acc[oo * 7 + b]);                  \
        }                                                                     \
    }

    ISSUE_C(0, 0);                       // prologue
    #pragma unroll 1
    for (int c = 0; c < 8; ++c) {
        const int p = c & 1;
        if (c < 7) {
            ISSUE_C(c + 1, p ^ 1);       // prefetch next channel
            // wait for channel c's 27 (tolerate the 27 just issued in flight)
            asm volatile("s_waitcnt vmcnt(27)" ::: "memory");
        } else {
            asm volatile("s_waitcnt vmcnt(0)" ::: "memory");
        }
        __builtin_amdgcn_sched_barrier(0);   // rule #18: no hoist past wait
        COMPUTE_C(c, p);
    }

    // all waves done with staging slices before qs aliases them
    __syncthreads();
    float* qs = smem;                    // OG*7*HW = 17920 B, aliased
    #pragma unroll
    for (int i = 0; i < OG * 7; ++i) qs[i * HW + tid] = acc[i];
    __syncthreads();

    // ---------------- stage 2: b-outer, basis via scalar loads ----------------
    const int h = tid / 40;
    const int w = tid - h * 40;
    const int ii = min(max(h, 1), 6) - 1;    // 0..5
    const int jj = min(max(w, 1), 38) - 1;   // 0..37
    const bool border = (h == 0) | (h == 7) | (w == 0) | (w == 39);
    const int base_hw = ii * 40 + jj;

    float s[OG][12];
    #pragma unroll
    for (int oo = 0; oo < OG; ++oo)
        #pragma unroll
        for (int g = 0; g < 12; ++g) s[oo][g] = 0.f;

    #pragma unroll 1
    for (int b = 0; b < 7; ++b) {
        float qw[OG][9];
        #pragma unroll
        for (int uv = 0; uv < 9; ++uv) {
            const int u = uv / 3, v = uv - (uv / 3) * 3;
            #pragma unroll
            for (int oo = 0; oo < OG; ++oo)
                qw[oo][uv] = qs[(oo * 7 + b) * HW + base_hw + u * 40 + v];
        }
        const float* bb = basis + b * 9;
        #pragma unroll
        for (int g = 0; g < 12; ++g) {
            #pragma unroll
            for (int uv = 0; uv < 9; ++uv) {
                const float bv = bb[g * 63 + uv];   // uniform -> s_load (K$-hit)
                #pragma unroll
                for (int oo = 0; oo < OG; ++oo)
                    s[oo][g] = fmaf(qw[oo][uv], bv, s[oo][g]);
            }
        }
    }

    // bias sums (wave-uniform s_loads, outside hot loop)
    float bs[OG];
    #pragma unroll
    for (int oo = 0; oo < OG; ++oo) {
        float t = 0.f;
        #pragma unroll
        for (int i = 0; i < 27; ++i) t += bias[(o0 + oo) * 27 + i];
        bs[oo] = t;
    }

    const int out_xyz = ((xo + 1) * 144 + (yo + 1) * 12 + (zo + 1)) * HW + tid;

    #pragma unroll
    for (int oo = 0; oo < OG; ++oo)
        #pragma unroll
        for (int g = 0; g < 12; ++g) {
            float val = (border ? s[oo][(g + 1) % 12] : s[oo][g]) + bs[oo];
            out[(g * 8 + o0 + oo) * (1728 * HW) + out_xyz] = val;
        }
}

extern "C" void kernel_launch(void* const* d_in, const int* in_sizes, int n_in,
                              void* d_out, int out_size, void* d_ws, size_t ws_size,
                              hipStream_t stream)
{
    const float* x      = (const float*)d_in[0];
    const float* weight = (const float*)d_in[1];
    const float* bias   = (const float*)d_in[2];
    const float* basis  = (const float*)d_in[3];
    float* out = (float*)d_out;

    fused_kernel<<<NPAD, 320, 0, stream>>>(x, weight, bias, basis, out);
}

// Round 13
// 412.428 us; speedup vs baseline: 1.4192x; 1.4192x over previous
//
#include <hip/hip_runtime.h>

// gConv3d separable factorization:
//   q[n,o,b,h,w]   = sum_{c,f} x[c, n+f, h, w] * weight[o,c,f,b]        (K=216)
//   s[n,g,o,ii,jj] = sum_{b,u,v} q[n,o,b,ii+u,jj+v] * basis[g][(b,u,v)] (K=63)
//   out[g*8+o, xo+1,yo+1,zo+1, h, w] = s[n, T(g,h,w), o, clip(h)-1, clip(w)-1] + bias_sum[o]
// T(g,h,w) = (g+1)%12 on the (h,w) border, else g. Non-interior xyz = 0.
//
// R17. R16 failed with absmax 5.75 (sporadic corruption, addressing fine).
// Root cause: R14's identical pipeline measured VGPR=68; R16's (320,8)
// capped at 64 -> spill; SCRATCH OPS COUNT TOWARD VMCNT, so the counted
// s_waitcnt vmcnt(9) retired before group i's staging landed -> stale LDS
// reads. Two fixes:
//  (1) launch_bounds(320,7): cap 72 >= measured 68 need -> no spill.
//  (2) spill-ROBUST waits: vmcnt(0) at the TOP of each phase, before
//      issuing the next group. Window = one full compute phase, identical
//      to the counted scheme; but conservative against any stray VMEM.
//      Correctness no longer depends on instruction-exact codegen.
// Residency: VGPR<=72 -> 7 waves/SIMD -> 5 blocks/CU (25 waves), LDS 23040.
// R14 measured 10.8%/wave duty with 27-tap phases; 9-tap phases shorten the
// per-phase ds_read chain -> ~15-19%/wave x 6.25 waves/SIMD ~= saturation.
// Sentinels: WRITE_SIZE == 207360 KB exactly; VGPR 60-72 no spill;
// LDS 23040. Predict: VALUBusy 65-85%, dur ~95-130 us.

#define HW 320
#define OG 2          // o's per block (4 blocks per n)
#define NLOG 2916     // 729 n * 4 o-quarters
#define NPAD 2928     // 8 * 366

typedef __attribute__((address_space(3))) float       lds_f;
typedef __attribute__((address_space(1)))  const float glb_f;

__global__ __launch_bounds__(320, 7) void fused_kernel(
    const float* __restrict__ x, const float* __restrict__ weight,
    const float* __restrict__ bias, const float* __restrict__ basis,
    float* __restrict__ out)
{
    // staging: [buf][tap][tid] = 2*9*320 floats = 23040 B.
    // qs (OG*7*HW = 4480 floats = 17920 B) aliases the front after stage-1;
    // both transitions barrier-protected.
    __shared__ float smem[2 * 9 * 320];

    const int tid = threadIdx.x;
    // wave-uniform slice base (SGPR): w*64 for wave w. REQUIRED uniform for
    // the global_load_lds dest (R15 failed with a divergent dest).
    const int wslice = __builtin_amdgcn_readfirstlane(tid & ~63);

    // ---- border zero-fill (grid-strided, masked, coalesced) ----
    {
        float4* out4 = (float4*)out;
        const float4 z = make_float4(0.f, 0.f, 0.f, 0.f);
        for (int s = blockIdx.x * 320 + tid; s < 96 * 1728 * 80; s += NPAD * 320) {
            int row = s / 80;                      // go*1728 + xyz
            int xyz = row - (row / 1728) * 1728;
            int xi = xyz / 144;
            int r2 = xyz - xi * 144;
            int yi = r2 / 12;
            int zi = r2 - yi * 12;
            if (!((unsigned)(xi - 1) < 9u && (unsigned)(yi - 1) < 9u &&
                  (unsigned)(zi - 1) < 9u))
                out4[s] = z;
        }
    }

    // XCD-aware swizzle: contiguous logical range per XCD; all 4 o-blocks of
    // one n stay on the same XCD (they share all 216 x taps).
    const int xcd  = blockIdx.x & 7;
    const int slot = blockIdx.x >> 3;
    const int logical = xcd * (NPAD / 8) + slot;
    if (logical >= NLOG) return;

    const int n  = logical >> 2;
    const int o0 = (logical & 3) * OG;
    const int xo = n / 81;
    const int rem = n - xo * 81;
    const int yo = rem / 9;
    const int zo = rem - yo * 9;

    // ---------------- stage 1: async LDS pipeline, 9-tap groups ------------
    float acc[OG * 7];
    #pragma unroll
    for (int i = 0; i < OG * 7; ++i) acc[i] = 0.f;

    // per-lane global source base (+tid = wave*64 + lane);
    // LDS dest = wave-uniform slice base, HW adds lane*4.
    const float* xb = x + ((xo * 12 + yo) * 12 + zo) * HW + tid;

    // issue the 9 tap-slices of (channel cc, fi-group gg) into buffer pp
    #define ISSUE_G(cc, gg, pp) {                                             \
        const float* xsrc = xb + ((cc) * 1728 + (gg) * 144) * HW;             \
        _Pragma("unroll")                                                     \
        for (int t = 0; t < 9; ++t) {                                         \
            const int fj = t / 3, fk = t % 3;                                 \
            __builtin_amdgcn_global_load_lds(                                 \
                (glb_f*)(xsrc + (fj * 12 + fk) * HW),                         \
                (lds_f*)&smem[(pp) * 2880 + t * 320 + wslice],                \
                4, 0, 0);                                                     \
        }                                                                     \
    }

    #define COMPUTE_G(cc, gg, pp) {                                           \
        const float* wg = weight + o0 * 1512 + (cc) * 189 + (gg) * 63;        \
        _Pragma("unroll")                                                     \
        for (int t = 0; t < 9; ++t) {                                         \
            const int fj = t / 3, fk = t % 3;                                 \
            float xval = smem[(pp) * 2880 + t * 320 + tid];                   \
            const float* wp = wg + fj * 21 + fk * 7;  /* uniform -> s_load */ \
            _Pragma("unroll")                                                 \
            for (int oo = 0; oo < OG; ++oo)                                   \
                _Pragma("unroll")                                             \
                for (int b = 0; b < 7; ++b)                                   \
                    acc[oo * 7 + b] = fmaf(xval, wp[oo * 1512 + b],           \
                                           acc[oo * 7 + b]);                  \
        }                                                                     \
    }

    ISSUE_G(0, 0, 0);                    // prologue: G0 in flight
    #pragma unroll 1
    for (int c = 0; c < 8; ++c) {
        #pragma unroll
        for (int g = 0; g < 3; ++g) {
            const int p = (c + g) & 1;   // buffer parity of current group
            // SPILL-ROBUST wait: everything outstanding (== current group,
            // issued one full phase ago, + any stray VMEM) has landed.
            asm volatile("s_waitcnt vmcnt(0)" ::: "memory");
            __builtin_amdgcn_sched_barrier(0);   // no ds_read hoist past wait
            // prefetch next group into the other buffer; flies under the
            // 126-FMA compute below, waited at the top of the next phase.
            if (g < 2)      ISSUE_G(c, g + 1, p ^ 1)
            else if (c < 7) ISSUE_G(c + 1, 0, p ^ 1)
            COMPUTE_G(c, g, p);
        }
    }

    // all waves done with staging before qs aliases it
    __syncthreads();
    float* qs = smem;                    // 17920 B, aliased
    #pragma unroll
    for (int i = 0; i < OG * 7; ++i) qs[i * HW + tid] = acc[i];
    __syncthreads();

    // ---------------- stage 2: b-outer, basis via scalar loads ----------------
    const int h = tid / 40;
    const int w = tid - h * 40;
    const int ii = min(max(h, 1), 6) - 1;    // 0..5
    const int jj = min(max(w, 1), 38) - 1;   // 0..37
    const bool border = (h == 0) | (h == 7) | (w == 0) | (w == 39);
    const int base_hw = ii * 40 + jj;

    float s[OG][12];
    #pragma unroll
    for (int oo = 0; oo < OG; ++oo)
        #pragma unroll
        for (int g = 0; g < 12; ++g) s[oo][g] = 0.f;

    #pragma unroll 1
    for (int b = 0; b < 7; ++b) {
        float qw[OG][9];
        #pragma unroll
        for (int uv = 0; uv < 9; ++uv) {
            const int u = uv / 3, v = uv - (uv / 3) * 3;
            #pragma unroll
            for (int oo = 0; oo < OG; ++oo)
                qw[oo][uv] = qs[(oo * 7 + b) * HW + base_hw + u * 40 + v];
        }
        const float* bb = basis + b * 9;
        #pragma unroll
        for (int g = 0; g < 12; ++g) {
            #pragma unroll
            for (int uv = 0; uv < 9; ++uv) {
                const float bv = bb[g * 63 + uv];   // uniform -> s_load (K$-hit)
                #pragma unroll
                for (int oo = 0; oo < OG; ++oo)
                    s[oo][g] = fmaf(qw[oo][uv], bv, s[oo][g]);
            }
        }
    }

    // bias sums (wave-uniform s_loads, outside hot loop)
    float bs[OG];
    #pragma unroll
    for (int oo = 0; oo < OG; ++oo) {
        float t = 0.f;
        #pragma unroll
        for (int i = 0; i < 27; ++i) t += bias[(o0 + oo) * 27 + i];
        bs[oo] = t;
    }

    const int out_xyz = ((xo + 1) * 144 + (yo + 1) * 12 + (zo + 1)) * HW + tid;

    #pragma unroll
    for (int oo = 0; oo < OG; ++oo)
        #pragma unroll
        for (int g = 0; g < 12; ++g) {
            float val = (border ? s[oo][(g + 1) % 12] : s[oo][g]) + bs[oo];
            out[(g * 8 + o0 + oo) * (1728 * HW) + out_xyz] = val;
        }
}

extern "C" void kernel_launch(void* const* d_in, const int* in_sizes, int n_in,
                              void* d_out, int out_size, void* d_ws, size_t ws_size,
                              hipStream_t stream)
{
    const float* x      = (const float*)d_in[0];
    const float* weight = (const float*)d_in[1];
    const float* bias   = (const float*)d_in[2];
    const float* basis  = (const float*)d_in[3];
    float* out = (float*)d_out;

    fused_kernel<<<NPAD, 320, 0, stream>>>(x, weight, bias, basis, out);
}